// Round 4
// baseline (205.260 us; speedup 1.0000x reference)
//
#include <hip/hip_runtime.h>

// Problem constants (match reference)
#define B_ 64
#define T_ 4096
#define C_ 8
#define K_ 150

constexpr int TPB     = 256;  // threads per block
constexpr int TCHUNK  = 256;  // timesteps per block (1 per thread)
constexpr int NACC    = 27;   // 24 num (3k x 8c) + 3 den per lane
constexpr int RSTRIDE = 29;   // odd stride -> <=2-way LDS bank aliasing (free)
constexpr int PACKW   = 16;   // floats per packed centroid row (64 B aligned)

#if __has_builtin(__builtin_amdgcn_exp2f)
#define EXP2F(x) __builtin_amdgcn_exp2f(x)
#else
#define EXP2F(x) __expf((x) * 0.6931471805599453f)
#endif

__device__ __forceinline__ float readlane_f(float v, int l) {
    return __int_as_float(__builtin_amdgcn_readlane(__float_as_int(v), l));
}

// Fused: zero accumulators + pack centroids into exp2 domain.
// pack[k][0..7] = 2*log2e*c_k,  pack[k][8] = log2e*|c_k|^2  (64 B stride)
__global__ void prep_kernel(const float* __restrict__ cent,
                            float* __restrict__ patch,      // [B,K,C] zeroed
                            float* __restrict__ den_g,      // [B,K]   zeroed
                            float* __restrict__ pack) {     // [K,16]
    const float LOG2E = 1.4426950408889634f;
    int i = blockIdx.x * blockDim.x + threadIdx.x;
    int n_patch = B_ * K_ * C_;           // 76800
    int n_total = n_patch + B_ * K_;      // +9600
    if (i < n_patch)      patch[i] = 0.0f;
    else if (i < n_total) den_g[i - n_patch] = 0.0f;
    if (i < K_) {
        float s = 0.0f;
#pragma unroll
        for (int c = 0; c < C_; ++c) {
            float v = cent[i * C_ + c];
            pack[i * PACKW + c] = 2.0f * LOG2E * v;
            s += v * v;
        }
        pack[i * PACKW + 8] = LOG2E * s;
    }
}

__global__ __launch_bounds__(TPB) void softkmeans_main(
        const float* __restrict__ x,        // [B,T,C]
        const float* __restrict__ pack,     // [K,16] packed centroids
        float* __restrict__ assign_out,     // [B,T,K]
        float* __restrict__ num_g,          // [B,K,C] accumulator (in d_out)
        float* __restrict__ den_g) {        // [B,K]   accumulator (in d_ws)
    __shared__ float red[64 * RSTRIDE];    // 7.4 KB, epilogue only (no hot-loop LDS)

    const int bx    = blockIdx.x;
    const int b     = bx >> 4;             // 16 chunks per batch
    const int chunk = bx & 15;
    const int t0    = chunk * TCHUNK;
    const int tid   = threadIdx.x;
    const int wave  = tid >> 6;
    const int lane  = tid & 63;

    // Per-thread x (thread tid owns t_local = tid): coalesced dwordx4 pairs.
    const float4* xsrc = (const float4*)(x + ((size_t)b * T_ + t0) * C_);
    float4 xa = xsrc[2 * tid];
    float4 xb = xsrc[2 * tid + 1];

    // ---- pass-2 centroid fragments: lane owns k in {lane, lane+64, lane+128}
    float cen[3][C_];
    float csq2[3];
#pragma unroll
    for (int j = 0; j < 3; ++j) {
        int k = lane + 64 * j;
        if (k < K_) {
            const float4* p4 = (const float4*)(pack + k * PACKW);
            float4 c0 = p4[0], c1 = p4[1];
            cen[j][0] = c0.x; cen[j][1] = c0.y; cen[j][2] = c0.z; cen[j][3] = c0.w;
            cen[j][4] = c1.x; cen[j][5] = c1.y; cen[j][6] = c1.z; cen[j][7] = c1.w;
            csq2[j] = pack[k * PACKW + 8];
        } else {
#pragma unroll
            for (int c = 0; c < C_; ++c) cen[j][c] = 0.0f;
            csq2[j] = 1e30f;   // exp2(-1e30) = 0: dead lane contributes nothing
        }
    }

    // ---- pass 1: per-lane softmax denominator. Centroids come in on the
    // SCALAR pipe (uniform index -> s_load_dwordx*), FMAs use the SGPR operand.
    // Zero LDS, zero cross-lane ops; 150 independent iterations.
    float s1a = 0.0f, s1b = 0.0f;
#pragma unroll 2
    for (int kk = 0; kk < K_; ++kk) {
        int k = __builtin_amdgcn_readfirstlane(kk);   // force wave-uniform addr
        const float* pk = pack + k * PACKW;
        float acc = -pk[8];
        acc = fmaf(pk[0], xa.x, acc); acc = fmaf(pk[1], xa.y, acc);
        acc = fmaf(pk[2], xa.z, acc); acc = fmaf(pk[3], xa.w, acc);
        acc = fmaf(pk[4], xb.x, acc); acc = fmaf(pk[5], xb.y, acc);
        acc = fmaf(pk[6], xb.z, acc); acc = fmaf(pk[7], xb.w, acc);
        if (kk & 1) s1b += EXP2F(acc); else s1a += EXP2F(acc);
    }
    float inv_own = __builtin_amdgcn_rcpf(s1a + s1b); // rel err ~1e-7 vs 2.4e-3 tol

    // ---- pass 2: k-ownership. x and inv arrive via v_readlane from this
    // wave's own pass-1 registers (wave w owns exactly t in [w*64, w*64+64)).
    float num[3][C_] = {};
    float den[3] = {0.0f, 0.0f, 0.0f};

    float* aout = assign_out + ((size_t)(b * T_ + t0 + wave * 64)) * K_ + lane;
#pragma unroll 2
    for (int tt = 0; tt < 64; ++tt) {
        float xv[C_];
        xv[0] = readlane_f(xa.x, tt); xv[1] = readlane_f(xa.y, tt);
        xv[2] = readlane_f(xa.z, tt); xv[3] = readlane_f(xa.w, tt);
        xv[4] = readlane_f(xb.x, tt); xv[5] = readlane_f(xb.y, tt);
        xv[6] = readlane_f(xb.z, tt); xv[7] = readlane_f(xb.w, tt);
        float inv = readlane_f(inv_own, tt);

        float e[3];
#pragma unroll
        for (int j = 0; j < 3; ++j) {
            float acc = -csq2[j];
#pragma unroll
            for (int c = 0; c < C_; ++c) acc = fmaf(cen[j][c], xv[c], acc);
            e[j] = EXP2F(acc);
        }

        float a0 = e[0] * inv, a1 = e[1] * inv, a2 = e[2] * inv;

        // Coalesced stores: 64 contiguous floats per instruction.
        aout[0]  = a0;
        aout[64] = a1;
        if (lane < K_ - 128) aout[128] = a2;
        aout += K_;

        den[0] += a0; den[1] += a1; den[2] += a2;
#pragma unroll
        for (int c = 0; c < C_; ++c) {
            num[0][c] = fmaf(a0, xv[c], num[0][c]);
            num[1][c] = fmaf(a1, xv[c], num[1][c]);
            num[2][c] = fmaf(a2, xv[c], num[2][c]);
        }
    }

    // ---- cross-wave reduction: serial wave-by-wave RMW into small LDS buffer
    float vals[NACC];
#pragma unroll
    for (int j = 0; j < 3; ++j) {
#pragma unroll
        for (int c = 0; c < C_; ++c) vals[j * C_ + c] = num[j][c];
        vals[24 + j] = den[j];
    }
    for (int w = 0; w < 4; ++w) {
        if (wave == w) {
            if (w == 0) {
#pragma unroll
                for (int i = 0; i < NACC; ++i) red[lane * RSTRIDE + i] = vals[i];
            } else {
#pragma unroll
                for (int i = 0; i < NACC; ++i) red[lane * RSTRIDE + i] += vals[i];
            }
        }
        __syncthreads();
    }

    if (tid < 64) {
#pragma unroll
        for (int j = 0; j < 3; ++j) {
            int k = lane + 64 * j;
            if (k < K_) {
#pragma unroll
                for (int c = 0; c < C_; ++c)
                    atomicAdd(&num_g[((size_t)b * K_ + k) * C_ + c],
                              red[lane * RSTRIDE + j * C_ + c]);
                atomicAdd(&den_g[b * K_ + k], red[lane * RSTRIDE + 24 + j]);
            }
        }
    }
}

// patch[i] = num[i] / (den[i/C] + 1e-8), in place on the num accumulator.
__global__ void finalize_patch(float* __restrict__ patch, const float* __restrict__ den_g) {
    int i = blockIdx.x * blockDim.x + threadIdx.x;
    if (i < B_ * K_ * C_) patch[i] = patch[i] / (den_g[i / C_] + 1e-8f);
}

extern "C" void kernel_launch(void* const* d_in, const int* in_sizes, int n_in,
                              void* d_out, int out_size, void* d_ws, size_t ws_size,
                              hipStream_t stream) {
    const float* x    = (const float*)d_in[0];   // [B,T,C]
    const float* cent = (const float*)d_in[1];   // [K,C]

    float* out        = (float*)d_out;
    float* patch      = out;                           // [B,K,C] = 76800 floats
    float* assign_out = out + (size_t)B_ * K_ * C_;    // [B,T,K]
    float* den_g      = (float*)d_ws;                  // [B,K] = 9600 floats
    float* pack       = den_g + B_ * K_;               // [K,16] = 2400 floats

    // 1) zero accumulators + pack centroids (d_out/d_ws poisoned before calls)
    int nz = B_ * K_ * C_ + B_ * K_;
    prep_kernel<<<(nz + TPB - 1) / TPB, TPB, 0, stream>>>(cent, patch, den_g, pack);

    // 2) fused distances -> softmax -> assignment write + num/den accumulation
    int grid = B_ * (T_ / TCHUNK);   // 64 * 16 = 1024 blocks
    softkmeans_main<<<grid, TPB, 0, stream>>>(x, pack, assign_out, patch, den_g);

    // 3) patch = num / (den + 1e-8)
    int np = B_ * K_ * C_;
    finalize_patch<<<(np + TPB - 1) / TPB, TPB, 0, stream>>>(patch, den_g);
}